// Round 18
// baseline (283.169 us; speedup 1.0000x reference)
//
#include <hip/hip_runtime.h>

// LowRankRotatedSpaceIntervention — v18: cross-tile read/write pipelining.
// out[b,:] = base[b,:] + (mask_b . ((source[b,:]-base[b,:]) @ W)) @ W^T
// B=16384, D=4096, R=64, 8 partitions of 8, 4 selected per row.
//
// R15-R17 resolved the 17-round mystery: the "6.3 TB/s achievable" number is
// COPY aggregate (read+write); the pure-read ceiling is ~3.1 TB/s, and all
// three structurally-different K1 variants sit at 90% of it. v11's 227.6us
// = ~165us GPU-wide read-only phase + ~65us write phase, SERIALIZED.
// v18 overlaps them: 256 blocks x 512 thr (8 waves), T=4 16-row tiles per
// block, pipelined: P1(t0); {P1(t_i+1) interleaved per-j with P2(t_i)} x3;
// P2(t3). During 3/4 of the run each CU issues reads AND writes (memcpy
// proves concurrency sums to 6.3). rm in LDS ping-pong (no global round
// trip). P1 = v16/v17 swapped-operand register-dbuf; P2 = v15-K2 wave-
// private groups; reduce = v17. Pre-commit: >=228us -> v11 is roofline.

#define D_DIM 4096
#define R_DIM 64
#define TPB   4                // tiles per block
#define BM2   32               // fallback rows/block

typedef short bf16vec8 __attribute__((ext_vector_type(8)));
typedef float f32x4v  __attribute__((ext_vector_type(4)));

__device__ __forceinline__ unsigned int f2bf_u(float f) {
  unsigned int u = __builtin_bit_cast(unsigned int, f);
  return (u + 0x7fffu + ((u >> 16) & 1u)) >> 16;   // RNE
}
__device__ __forceinline__ unsigned int pack2bf(float a, float b) {
  return f2bf_u(a) | (f2bf_u(b) << 16);
}
__device__ __forceinline__ void async_ld16(const void* g, void* l) {
  __builtin_amdgcn_global_load_lds(
      (const __attribute__((address_space(1))) void*)g,
      (__attribute__((address_space(3))) void*)l, 16, 0, 0);
}

__global__ __launch_bounds__(256)
void lrri_prep(const float* __restrict__ W, unsigned short* __restrict__ Wt,
               unsigned short* __restrict__ Wb) {
  const int idx = blockIdx.x * blockDim.x + threadIdx.x;   // 0..65535
  const int k = idx >> 4;
  const int j = (idx & 15) * 4;
  float4 w = *(const float4*)(W + (size_t)k * R_DIM + j);
  ushort4 p;
  p.x = (unsigned short)f2bf_u(w.x);
  p.y = (unsigned short)f2bf_u(w.y);
  p.z = (unsigned short)f2bf_u(w.z);
  p.w = (unsigned short)f2bf_u(w.w);
  *(ushort4*)(Wb + (size_t)k * R_DIM + j) = p;     // [4096][64] bf16
  Wt[(size_t)(j + 0) * D_DIM + k] = p.x;           // [64][4096] bf16
  Wt[(size_t)(j + 1) * D_DIM + k] = p.y;
  Wt[(size_t)(j + 2) * D_DIM + k] = p.z;
  Wt[(size_t)(j + 3) * D_DIM + k] = p.w;
}

// ==================== pipelined fused kernel =============================
__global__ __launch_bounds__(512, 2)
void lrri_pipe(const float* __restrict__ base, const float* __restrict__ srcp,
               const int* __restrict__ subs,
               const unsigned short* __restrict__ Wt_bf,   // [64][4096]
               const unsigned short* __restrict__ Wb_bf,   // [4096][64]
               float* __restrict__ out)
{
  __shared__ __align__(16) float part[8][64 * 17];          // 34816 B
  __shared__ __align__(16) unsigned short rmb[2][16 * 64];  //  4096 B
  __shared__ __align__(16) float cbufs[8][16 * 72];         // 36864 B

  const int tid  = threadIdx.x;
  const int wave = tid >> 6;            // 0..7
  const int lane = tid & 63;
  const int l4   = lane & 15;
  const int g    = lane >> 4;
  const int t0   = blockIdx.x * TPB;    // first tile (16 rows each)
  const int kq0  = wave * 512;          // wave's K-eighth / col window
  float* cbuf = cbufs[wave];

  f32x4v acc[4];

  // ---- P1 pieces (v16/v17-verified swapped-operand form) ----------------
  // C[j][row]: A = W^T fragment (Wt_bf row t*16+l4, contiguous, L2-hot),
  // B = diff fragment (8 consecutive fp32 of batch row l4).
  auto loadd = [&](int tile, int ch, float4 (&vb)[4], float4 (&vs)[4]) {
    const long rowA = ((long)tile * 16 + l4) * (long)D_DIM;
    const long colf = kq0 + ch * 64;
    #pragma unroll
    for (int q = 0; q < 4; ++q) {          // q = s*2 + half
      const long off = rowA + colf + (q >> 1) * 32 + g * 8 + (q & 1) * 4;
      vb[q] = *(const float4*)(base + off);
      vs[q] = *(const float4*)(srcp + off);
    }
  };
  auto comp = [&](int ch, const float4 (&vb)[4], const float4 (&vs)[4]) {
    const long colf = kq0 + ch * 64;
    uint4 df[2];
    #pragma unroll
    for (int s = 0; s < 2; ++s) {
      df[s].x = pack2bf(vs[s*2].x - vb[s*2].x, vs[s*2].y - vb[s*2].y);
      df[s].y = pack2bf(vs[s*2].z - vb[s*2].z, vs[s*2].w - vb[s*2].w);
      df[s].z = pack2bf(vs[s*2+1].x - vb[s*2+1].x, vs[s*2+1].y - vb[s*2+1].y);
      df[s].w = pack2bf(vs[s*2+1].z - vb[s*2+1].z, vs[s*2+1].w - vb[s*2+1].w);
    }
    #pragma unroll
    for (int t = 0; t < 4; ++t) {
      #pragma unroll
      for (int s = 0; s < 2; ++s) {
        uint4 wf = *(const uint4*)(Wt_bf + (size_t)(t * 16 + l4) * D_DIM +
                                   colf + s * 32 + g * 8);   // L2-hot
        acc[t] = __builtin_amdgcn_mfma_f32_16x16x32_bf16(
            __builtin_bit_cast(bf16vec8, wf),      // A = W^T fragment
            __builtin_bit_cast(bf16vec8, df[s]),   // B = diff fragment
            acc[t], 0, 0, 0);
      }
    }
  };
  auto savepart = [&]() {
    #pragma unroll
    for (int t = 0; t < 4; ++t)
      #pragma unroll
      for (int i = 0; i < 4; ++i)
        part[wave][(t * 16 + g * 4 + i) * 17 + l4] = acc[t][i];
  };
  // reduce 8 K-eighths + mask -> rmb[rbuf]   (512 thr: 16 rows x 32 j-pairs)
  auto reduce = [&](int tile, int rbuf) {
    const int row = tid >> 5, j0 = (tid & 31) * 2;
    int4 sb = *(const int4*)(subs + (size_t)(tile * 16 + row) * 4);
    unsigned mbits = (1u << sb.x) | (1u << sb.y) | (1u << sb.z) | (1u << sb.w);
    unsigned short v[2];
    #pragma unroll
    for (int jj = 0; jj < 2; ++jj) {
      const int j = j0 + jj;
      float sum = 0.f;
      #pragma unroll
      for (int w = 0; w < 8; ++w) sum += part[w][j * 17 + row];
      v[jj] = ((mbits >> (j >> 3)) & 1u) ? (unsigned short)f2bf_u(sum)
                                         : (unsigned short)0;
    }
    *(unsigned int*)(&rmb[rbuf][row * 64 + j0]) =
        (unsigned)v[0] | ((unsigned)v[1] << 16);
  };

  // ---- P2 group (v15-K2-verified, wave-private cbuf, no barriers) --------
  auto p2group = [&](int tile, int ga, const uint4 (&a2)[2]) {
    const int cbase = kq0 + ga * 64;
    const long rb = (long)tile * 16;
    float4 bb[4];
    #pragma unroll
    for (int v2 = 0; v2 < 4; ++v2) {
      const int r = g + v2 * 4;
      bb[v2] = *(const float4*)(base + (rb + r) * (long)D_DIM + cbase + l4 * 4);
    }
    f32x4v a[4];
    #pragma unroll
    for (int t = 0; t < 4; ++t) a[t] = (f32x4v){0.f, 0.f, 0.f, 0.f};
    #pragma unroll
    for (int t = 0; t < 4; ++t) {
      #pragma unroll
      for (int s = 0; s < 2; ++s) {
        uint4 bfrag = *(const uint4*)(Wb_bf +
            (size_t)(cbase + t * 16 + l4) * R_DIM + s * 32 + g * 8);
        a[t] = __builtin_amdgcn_mfma_f32_16x16x32_bf16(
            __builtin_bit_cast(bf16vec8, a2[s]),
            __builtin_bit_cast(bf16vec8, bfrag), a[t], 0, 0, 0);
      }
    }
    #pragma unroll
    for (int t = 0; t < 4; ++t)
      #pragma unroll
      for (int i = 0; i < 4; ++i)
        cbuf[(g * 4 + i) * 72 + t * 16 + l4] = a[t][i];
    #pragma unroll
    for (int v2 = 0; v2 < 4; ++v2) {
      const int r = g + v2 * 4;
      f32x4v cv = *(const f32x4v*)(cbuf + r * 72 + l4 * 4);
      float4 o;
      o.x = cv[0] + bb[v2].x;
      o.y = cv[1] + bb[v2].y;
      o.z = cv[2] + bb[v2].z;
      o.w = cv[3] + bb[v2].w;
      *(float4*)(out + (rb + r) * (long)D_DIM + cbase + l4 * 4) = o;
    }
  };

  // ================= pipeline =============================================
  float4 vb[2][4], vs[2][4];

  // prologue: P1(tile0) full, register double-buffered
  {
    const int o1 = (blockIdx.x * 5) & 7;
    #pragma unroll
    for (int t = 0; t < 4; ++t) acc[t] = (f32x4v){0.f, 0.f, 0.f, 0.f};
    loadd(t0, (0 + o1) & 7, vb[0], vs[0]);
    #pragma unroll
    for (int j = 0; j < 8; ++j) {
      if (j < 7) loadd(t0, (j + 1 + o1) & 7, vb[(j + 1) & 1], vs[(j + 1) & 1]);
      comp((j + o1) & 7, vb[j & 1], vs[j & 1]);
    }
    savepart();
  }
  __syncthreads();
  reduce(t0, 0);
  __syncthreads();

  // main: for i in 0..2: P1(tile i+1) interleaved with P2(tile i)
  #pragma unroll 1
  for (int i = 0; i < TPB - 1; ++i) {
    uint4 a2[2];
    #pragma unroll
    for (int s = 0; s < 2; ++s)
      a2[s] = *(const uint4*)(&rmb[i & 1][l4 * 64 + s * 32 + g * 8]);
    #pragma unroll
    for (int t = 0; t < 4; ++t) acc[t] = (f32x4v){0.f, 0.f, 0.f, 0.f};
    const int o1 = (blockIdx.x * 5 + (i + 1) * 3) & 7;
    const int o2 = (blockIdx.x * 3 + i) & 7;
    loadd(t0 + i + 1, (0 + o1) & 7, vb[0], vs[0]);
    #pragma unroll
    for (int j = 0; j < 8; ++j) {
      if (j < 7)
        loadd(t0 + i + 1, (j + 1 + o1) & 7, vb[(j + 1) & 1], vs[(j + 1) & 1]);
      p2group(t0 + i, (j + o2) & 7, a2);      // writes overlap next reads
      comp((j + o1) & 7, vb[j & 1], vs[j & 1]);
    }
    savepart();
    __syncthreads();
    reduce(t0 + i + 1, (i + 1) & 1);
    __syncthreads();
  }

  // tail: P2(tile3) from rmb[(TPB-1)&1]
  {
    uint4 a2[2];
    #pragma unroll
    for (int s = 0; s < 2; ++s)
      a2[s] = *(const uint4*)(&rmb[(TPB - 1) & 1][l4 * 64 + s * 32 + g * 8]);
    const int o2 = (blockIdx.x * 3 + (TPB - 1)) & 7;
    #pragma unroll
    for (int j = 0; j < 8; ++j)
      p2group(t0 + TPB - 1, (j + o2) & 7, a2);
  }
}

// ===================== fused fallback (no ws) [v15 verbatim] ==============
__global__ __launch_bounds__(256, 2)
void lrri_fused_nows(const float* __restrict__ base, const float* __restrict__ srcp,
                     const float* __restrict__ W, const int* __restrict__ subs,
                     float* __restrict__ out)
{
  __shared__ __align__(16) unsigned char smem[70144];
  const int tid  = threadIdx.x;
  const int wave = tid >> 6;
  const int lane = tid & 63;
  const int l4   = lane & 15;
  const int g    = lane >> 4;
  const int rh   = wave >> 1;
  const int kh   = wave & 1;
  const long rowbase = (long)blockIdx.x * BM2;
  const long rowg    = rowbase + rh * 16;
  unsigned char* wbuf = smem + wave * 16384;
  const int off1 = (blockIdx.x * 7) & 63;
  const int off2 = (blockIdx.x * 5) & 15;

  f32x4v acc[4];
  #pragma unroll
  for (int t = 0; t < 4; ++t) acc[t] = (f32x4v){0.f, 0.f, 0.f, 0.f};

  #pragma unroll 1
  for (int c = 0; c < 64; ++c) {
    const int ch = (c + off1) & 63;
    unsigned char* buf = wbuf + (c & 1) * 8192;
    const long colf = kh * 2048 + ch * 32;
    #pragma unroll
    for (int q = 0; q < 2; ++q) {
      const int r = q * 8 + (lane >> 3);
      const unsigned b = ((unsigned)((lane & 7) * 16)) ^ ((unsigned)(r & 7) << 4);
      const long goff = (rowg + r) * (long)D_DIM + colf + (b >> 2);
      async_ld16(base + goff, buf + q * 1024);
      async_ld16(srcp + goff, buf + 2048 + q * 1024);
    }
    asm volatile("s_waitcnt vmcnt(0)" ::: "memory");
    __builtin_amdgcn_sched_barrier(0);
    const unsigned sw = (unsigned)((l4 & 7) << 4);
    const unsigned c0 = ((unsigned)(g * 32)) ^ sw;
    const unsigned c1 = ((unsigned)(g * 32 + 16)) ^ sw;
    float4 fb0 = *(const float4*)(buf + l4 * 128 + c0);
    float4 fb1 = *(const float4*)(buf + l4 * 128 + c1);
    float4 fs0 = *(const float4*)(buf + 2048 + l4 * 128 + c0);
    float4 fs1 = *(const float4*)(buf + 2048 + l4 * 128 + c1);
    uint4 af;
    af.x = pack2bf(fs0.x - fb0.x, fs0.y - fb0.y);
    af.y = pack2bf(fs0.z - fb0.z, fs0.w - fb0.w);
    af.z = pack2bf(fs1.x - fb1.x, fs1.y - fb1.y);
    af.w = pack2bf(fs1.z - fb1.z, fs1.w - fb1.w);
    #pragma unroll
    for (int t = 0; t < 4; ++t) {
      unsigned int pq[4];
      #pragma unroll
      for (int e2 = 0; e2 < 4; ++e2) {
        float wa = W[(size_t)(colf + g * 8 + e2 * 2    ) * R_DIM + t * 16 + l4];
        float wb = W[(size_t)(colf + g * 8 + e2 * 2 + 1) * R_DIM + t * 16 + l4];
        pq[e2] = pack2bf(wa, wb);
      }
      uint4 wf; wf.x = pq[0]; wf.y = pq[1]; wf.z = pq[2]; wf.w = pq[3];
      acc[t] = __builtin_amdgcn_mfma_f32_16x16x32_bf16(
          __builtin_bit_cast(bf16vec8, af),
          __builtin_bit_cast(bf16vec8, wf), acc[t], 0, 0, 0);
    }
  }

  {
    float* part = (float*)wbuf;
    #pragma unroll
    for (int t = 0; t < 4; ++t)
      #pragma unroll
      for (int i = 0; i < 4; ++i)
        part[(g * 4 + i) * 72 + t * 16 + l4] = acc[t][i];
  }
  __syncthreads();

  {
    const int row = tid >> 3, jg = tid & 7;
    const int lr  = row & 15;
    const float* pa = (const float*)(smem + ((row >> 4) * 2 + 0) * 16384);
    const float* pb = (const float*)(smem + ((row >> 4) * 2 + 1) * 16384);
    int4 sb = *(const int4*)(subs + (rowbase + row) * 4);
    unsigned mbits = (1u << sb.x) | (1u << sb.y) | (1u << sb.z) | (1u << sb.w);
    unsigned short v[8];
    #pragma unroll
    for (int jj = 0; jj < 8; ++jj) {
      const int j = jg * 8 + jj;
      float sum = pa[lr * 72 + j] + pb[lr * 72 + j];
      v[jj] = ((mbits >> (j >> 3)) & 1u) ? (unsigned short)f2bf_u(sum)
                                         : (unsigned short)0;
    }
    uint4 pk;
    pk.x = (unsigned)v[0] | ((unsigned)v[1] << 16);
    pk.y = (unsigned)v[2] | ((unsigned)v[3] << 16);
    pk.z = (unsigned)v[4] | ((unsigned)v[5] << 16);
    pk.w = (unsigned)v[6] | ((unsigned)v[7] << 16);
    *(uint4*)(smem + 65536 + row * 144 + jg * 16) = pk;
  }
  __syncthreads();

  uint4 a2[2][2];
  #pragma unroll
  for (int m = 0; m < 2; ++m)
    #pragma unroll
    for (int s = 0; s < 2; ++s)
      a2[m][s] = *(const uint4*)(smem + 65536 + (m * 16 + l4) * 144 +
                                 s * 64 + g * 16);
  float* cbuf = (float*)wbuf;
  #pragma unroll 1
  for (int grp = 0; grp < 16; ++grp) {
    const int ga = (grp + off2) & 15;
    const int cbase = wave * 1024 + ga * 64;
    float4 bb[8];
    #pragma unroll
    for (int v2 = 0; v2 < 8; ++v2) {
      const int r = g + v2 * 4;
      bb[v2] = *(const float4*)(base + (rowbase + r) * D_DIM + cbase + l4 * 4);
    }
    f32x4v a[2][4];
    #pragma unroll
    for (int m = 0; m < 2; ++m)
      #pragma unroll
      for (int t = 0; t < 4; ++t) a[m][t] = (f32x4v){0.f, 0.f, 0.f, 0.f};
    #pragma unroll
    for (int t = 0; t < 4; ++t) {
      #pragma unroll
      for (int s = 0; s < 2; ++s) {
        const float* wp = W + (size_t)(cbase + t * 16 + l4) * R_DIM + s * 32 + g * 8;
        float4 wa = *(const float4*)(wp);
        float4 wb2 = *(const float4*)(wp + 4);
        uint4 bfrag;
        bfrag.x = pack2bf(wa.x, wa.y); bfrag.y = pack2bf(wa.z, wa.w);
        bfrag.z = pack2bf(wb2.x, wb2.y); bfrag.w = pack2bf(wb2.z, wb2.w);
        #pragma unroll
        for (int m = 0; m < 2; ++m)
          a[m][t] = __builtin_amdgcn_mfma_f32_16x16x32_bf16(
              __builtin_bit_cast(bf16vec8, a2[m][s]),
              __builtin_bit_cast(bf16vec8, bfrag), a[m][t], 0, 0, 0);
      }
    }
    #pragma unroll
    for (int m = 0; m < 2; ++m)
      #pragma unroll
      for (int t = 0; t < 4; ++t)
        #pragma unroll
        for (int i = 0; i < 4; ++i)
          cbuf[(m * 16 + g * 4 + i) * 72 + t * 16 + l4] = a[m][t][i];
    #pragma unroll
    for (int v2 = 0; v2 < 8; ++v2) {
      const int r = g + v2 * 4;
      f32x4v cv = *(const f32x4v*)(cbuf + r * 72 + l4 * 4);
      float4 o;
      o.x = cv[0] + bb[v2].x;
      o.y = cv[1] + bb[v2].y;
      o.z = cv[2] + bb[v2].z;
      o.w = cv[3] + bb[v2].w;
      *(float4*)(out + (rowbase + r) * D_DIM + cbase + l4 * 4) = o;
    }
  }
}

extern "C" void kernel_launch(void* const* d_in, const int* in_sizes, int n_in,
                              void* d_out, int out_size, void* d_ws, size_t ws_size,
                              hipStream_t stream) {
  const float* base = (const float*)d_in[0];
  const float* srcp = (const float*)d_in[1];
  const float* W    = (const float*)d_in[2];
  const int*   subs = (const int*)d_in[3];
  float* out = (float*)d_out;

  const size_t wconv = (size_t)2 * R_DIM * D_DIM * sizeof(unsigned short); // 1 MB
  if (d_ws && ws_size >= wconv) {
    unsigned short* Wt = (unsigned short*)d_ws;          // [64][4096] bf16
    unsigned short* Wb = Wt + (size_t)R_DIM * D_DIM;     // [4096][64] bf16
    lrri_prep<<<256, 256, 0, stream>>>(W, Wt, Wb);
    lrri_pipe<<<16384 / (16 * TPB), 512, 0, stream>>>(base, srcp, subs,
                                                      Wt, Wb, out);
  } else {
    lrri_fused_nows<<<16384 / BM2, 256, 0, stream>>>(base, srcp, W, subs, out);
  }
}

// Round 19
// 226.836 us; speedup vs baseline: 1.2483x; 1.2483x over previous
//
#include <hip/hip_runtime.h>

// LowRankRotatedSpaceIntervention — FINAL: v11 restored (best: 227.6 us).
// out[b,:] = base[b,:] + (mask_b . ((source[b,:]-base[b,:]) @ W)) @ W^T
// B=16384, D=4096, R=64, 8 partitions of 8, 4 selected per row.
//
// 18-round conclusion: the kernel is read-phase-bound at the machine's
// pure-read ceiling (~3.1 TB/s delivered; K1-isolated hit 90% of it across
// three structures). Occupancy (4-32 w/CU), pipeline depth (0-16 in flight,
// exact vmcnt ledgers), instruction shape (256B-1KB), W placement (reg/LDS/
// vmcnt-evicted), XCD remap, footprint (BM 4-64), phase split, and phase
// overlap (v18, -24%) are all measured-neutral or negative. v11 = fused
// single pass: phase-1 all-gload_lds ring-2 with exact VMWAIT(8), phase-2
// register-streamed with L3-warm base re-read, cross-block column stagger.

#define D_DIM 4096
#define R_DIM 64
#define BM    32
#define WAVESTG 16384            // per-wave: 2 chunk-slots x 8KB
#define OFF_RM  65536            // [32][72] bf16 = 4608 B
#define SMEM_BYTES 70144         // 2 blocks/CU

typedef short bf16vec8 __attribute__((ext_vector_type(8)));
typedef float f32x4v  __attribute__((ext_vector_type(4)));

#define VMWAIT(N)                                              \
  do {                                                         \
    asm volatile("s_waitcnt vmcnt(" #N ")" ::: "memory");      \
    __builtin_amdgcn_sched_barrier(0);                         \
  } while (0)

__device__ __forceinline__ unsigned int f2bf_u(float f) {
  unsigned int u = __builtin_bit_cast(unsigned int, f);
  return (u + 0x7fffu + ((u >> 16) & 1u)) >> 16;   // RNE
}
__device__ __forceinline__ unsigned int pack2bf(float a, float b) {
  return f2bf_u(a) | (f2bf_u(b) << 16);
}
__device__ __forceinline__ void async_ld16(const void* g, void* l) {
  __builtin_amdgcn_global_load_lds(
      (const __attribute__((address_space(1))) void*)g,
      (__attribute__((address_space(3))) void*)l, 16, 0, 0);
}

__global__ __launch_bounds__(256)
void lrri_prep(const float* __restrict__ W, unsigned short* __restrict__ Wt,
               unsigned short* __restrict__ Wb) {
  const int idx = blockIdx.x * blockDim.x + threadIdx.x;   // 0..65535
  const int k = idx >> 4;
  const int j = (idx & 15) * 4;
  float4 w = *(const float4*)(W + (size_t)k * R_DIM + j);
  ushort4 p;
  p.x = (unsigned short)f2bf_u(w.x);
  p.y = (unsigned short)f2bf_u(w.y);
  p.z = (unsigned short)f2bf_u(w.z);
  p.w = (unsigned short)f2bf_u(w.w);
  *(ushort4*)(Wb + (size_t)k * R_DIM + j) = p;     // [4096][64] bf16
  Wt[(size_t)(j + 0) * D_DIM + k] = p.x;           // [64][4096] bf16
  Wt[(size_t)(j + 1) * D_DIM + k] = p.y;
  Wt[(size_t)(j + 2) * D_DIM + k] = p.z;
  Wt[(size_t)(j + 3) * D_DIM + k] = p.w;
}

template<bool USE_WS>
__global__ __launch_bounds__(256, 2)
void lrri_fused(const float* __restrict__ base, const float* __restrict__ srcp,
                const float* __restrict__ W, const int* __restrict__ subs,
                const unsigned short* __restrict__ Wt_bf,   // [64][4096]
                const unsigned short* __restrict__ Wb_bf,   // [4096][64]
                float* __restrict__ out)
{
  __shared__ __align__(16) unsigned char smem[SMEM_BYTES];
  const int tid  = threadIdx.x;
  const int wave = tid >> 6;
  const int lane = tid & 63;
  const int l4   = lane & 15;
  const int g    = lane >> 4;
  const int rh   = wave >> 1;            // row-half: 16 rows
  const int kh   = wave & 1;             // K-half: 2048 cols
  const long rowbase = (long)blockIdx.x * BM;
  const long rowg    = rowbase + rh * 16;
  unsigned char* wbuf = smem + wave * WAVESTG;
  const int off1 = (blockIdx.x * 7) & 63;   // phase-1 chunk stagger
  const int off2 = (blockIdx.x * 5) & 15;   // phase-2 group stagger

  // ---------------- Phase 1: r = (src-base) @ W over this wave's K half ---
  // chunk = 32 cols. Slot layout (8KB): [0,2KB) base [16r][128B],
  // [2KB,4KB) src, [4KB,8KB) W slice [64j][64B]. All XOR-swizzled at source.
  f32x4v acc[4];
  #pragma unroll
  for (int t = 0; t < 4; ++t) acc[t] = (f32x4v){0.f, 0.f, 0.f, 0.f};

  auto stage = [&](int c) {                       // 8 gload_lds, order-pinned
    const int ch = (c + off1) & 63;               // rotated chunk id
    unsigned char* buf = wbuf + (c & 1) * 8192;
    const long colf = kh * 2048 + ch * 32;        // first float col
    #pragma unroll
    for (int q = 0; q < 2; ++q) {
      const int r = q * 8 + (lane >> 3);          // row_local
      const unsigned b = ((unsigned)((lane & 7) * 16)) ^ ((unsigned)(r & 7) << 4);
      const long goff = (rowg + r) * (long)D_DIM + colf + (b >> 2);
      async_ld16(base + goff, buf + q * 1024);
    }
    #pragma unroll
    for (int q = 0; q < 2; ++q) {
      const int r = q * 8 + (lane >> 3);
      const unsigned b = ((unsigned)((lane & 7) * 16)) ^ ((unsigned)(r & 7) << 4);
      const long goff = (rowg + r) * (long)D_DIM + colf + (b >> 2);
      async_ld16(srcp + goff, buf + 2048 + q * 1024);
    }
    // W slice [64j][32k bf16 = 64B]: 4 instrs; instr q covers j-rows 16q..+15
    #pragma unroll
    for (int q = 0; q < 4; ++q) {
      const int j = q * 16 + (lane >> 2);
      const unsigned kb = ((unsigned)((lane & 3) * 16)) ^ ((unsigned)(j & 3) << 4);
      const char* src = (const char*)Wt_bf + (size_t)j * (D_DIM * 2) +
                        colf * 2 + kb;
      async_ld16(src, buf + 4096 + q * 1024);
    }
  };

  auto compute = [&](int c) {
    const unsigned char* buf = wbuf + (c & 1) * 8192;
    const unsigned sw = (unsigned)((l4 & 7) << 4);
    const unsigned c0 = ((unsigned)(g * 32)) ^ sw;
    const unsigned c1 = ((unsigned)(g * 32 + 16)) ^ sw;
    float4 fb0 = *(const float4*)(buf + l4 * 128 + c0);
    float4 fb1 = *(const float4*)(buf + l4 * 128 + c1);
    float4 fs0 = *(const float4*)(buf + 2048 + l4 * 128 + c0);
    float4 fs1 = *(const float4*)(buf + 2048 + l4 * 128 + c1);
    uint4 af;
    af.x = pack2bf(fs0.x - fb0.x, fs0.y - fb0.y);
    af.y = pack2bf(fs0.z - fb0.z, fs0.w - fb0.w);
    af.z = pack2bf(fs1.x - fb1.x, fs1.y - fb1.y);
    af.w = pack2bf(fs1.z - fb1.z, fs1.w - fb1.w);
    const unsigned wsl = ((unsigned)(g * 16)) ^ ((unsigned)(l4 & 3) << 4);
    #pragma unroll
    for (int t = 0; t < 4; ++t) {
      uint4 wf = *(const uint4*)(buf + 4096 + (t * 16 + l4) * 64 + wsl);
      acc[t] = __builtin_amdgcn_mfma_f32_16x16x32_bf16(
          __builtin_bit_cast(bf16vec8, af),
          __builtin_bit_cast(bf16vec8, wf), acc[t], 0, 0, 0);
    }
  };

  if constexpr (USE_WS) {
    stage(0); stage(1);                 // queue: 16
    #pragma unroll 1
    for (int c = 0; c < 62; ++c) {
      VMWAIT(8);                        // drains chunk c exactly
      compute(c);                       // MFMA lgkm-dep proves ds_reads done
      __builtin_amdgcn_sched_barrier(0);
      stage(c + 2);                     // refill slot (c&1)
    }
    VMWAIT(8);
    compute(62);
    VMWAIT(0);
    compute(63);
  } else {
    // fallback: serial full-drain; W from fp32 global via registers
    #pragma unroll 1
    for (int c = 0; c < 64; ++c) {
      const int ch = (c + off1) & 63;
      unsigned char* buf = wbuf + (c & 1) * 8192;
      const long colf = kh * 2048 + ch * 32;
      #pragma unroll
      for (int q = 0; q < 2; ++q) {
        const int r = q * 8 + (lane >> 3);
        const unsigned b = ((unsigned)((lane & 7) * 16)) ^ ((unsigned)(r & 7) << 4);
        const long goff = (rowg + r) * (long)D_DIM + colf + (b >> 2);
        async_ld16(base + goff, buf + q * 1024);
        async_ld16(srcp + goff, buf + 2048 + q * 1024);
      }
      VMWAIT(0);
      const unsigned sw = (unsigned)((l4 & 7) << 4);
      const unsigned c0 = ((unsigned)(g * 32)) ^ sw;
      const unsigned c1 = ((unsigned)(g * 32 + 16)) ^ sw;
      float4 fb0 = *(const float4*)(buf + l4 * 128 + c0);
      float4 fb1 = *(const float4*)(buf + l4 * 128 + c1);
      float4 fs0 = *(const float4*)(buf + 2048 + l4 * 128 + c0);
      float4 fs1 = *(const float4*)(buf + 2048 + l4 * 128 + c1);
      uint4 af;
      af.x = pack2bf(fs0.x - fb0.x, fs0.y - fb0.y);
      af.y = pack2bf(fs0.z - fb0.z, fs0.w - fb0.w);
      af.z = pack2bf(fs1.x - fb1.x, fs1.y - fb1.y);
      af.w = pack2bf(fs1.z - fb1.z, fs1.w - fb1.w);
      #pragma unroll
      for (int t = 0; t < 4; ++t) {
        unsigned int pq[4];
        #pragma unroll
        for (int e2 = 0; e2 < 4; ++e2) {
          float wa = W[(size_t)(colf + g * 8 + e2 * 2    ) * R_DIM + t * 16 + l4];
          float wb = W[(size_t)(colf + g * 8 + e2 * 2 + 1) * R_DIM + t * 16 + l4];
          pq[e2] = pack2bf(wa, wb);
        }
        uint4 wf; wf.x = pq[0]; wf.y = pq[1]; wf.z = pq[2]; wf.w = pq[3];
        acc[t] = __builtin_amdgcn_mfma_f32_16x16x32_bf16(
            __builtin_bit_cast(bf16vec8, af),
            __builtin_bit_cast(bf16vec8, wf), acc[t], 0, 0, 0);
      }
    }
  }

  // per-wave partials -> own staging area (dead now): [16][72] f32
  {
    float* part = (float*)wbuf;
    #pragma unroll
    for (int t = 0; t < 4; ++t)
      #pragma unroll
      for (int i = 0; i < 4; ++i)
        part[(g * 4 + i) * 72 + t * 16 + l4] = acc[t][i];
  }
  __syncthreads();

  // ---------------- Reduce K-halves + per-row partition mask --------------
  {
    const int row = tid >> 3, jg = tid & 7;     // 32 rows x 8 j-groups
    const int lr  = row & 15;
    const float* pa = (const float*)(smem + ((row >> 4) * 2 + 0) * WAVESTG);
    const float* pb = (const float*)(smem + ((row >> 4) * 2 + 1) * WAVESTG);
    int4 sb = *(const int4*)(subs + (rowbase + row) * 4);
    unsigned mbits = (1u << sb.x) | (1u << sb.y) | (1u << sb.z) | (1u << sb.w);
    unsigned short v[8];
    #pragma unroll
    for (int jj = 0; jj < 8; ++jj) {
      const int j = jg * 8 + jj;
      float sum = pa[lr * 72 + j] + pb[lr * 72 + j];
      v[jj] = ((mbits >> (j >> 3)) & 1u) ? (unsigned short)f2bf_u(sum)
                                         : (unsigned short)0;
    }
    uint4 pk;
    pk.x = (unsigned)v[0] | ((unsigned)v[1] << 16);
    pk.y = (unsigned)v[2] | ((unsigned)v[3] << 16);
    pk.z = (unsigned)v[4] | ((unsigned)v[5] << 16);
    pk.w = (unsigned)v[6] | ((unsigned)v[7] << 16);
    *(uint4*)(smem + OFF_RM + row * 144 + jg * 16) = pk;   // stride 72 shorts
  }
  __syncthreads();

  // ---------------- Phase 2: out = base(global) + rm @ W^T ----------------
  uint4 a2[2][2];     // [row-tile m][k-split s]
  #pragma unroll
  for (int m = 0; m < 2; ++m)
    #pragma unroll
    for (int s = 0; s < 2; ++s)
      a2[m][s] = *(const uint4*)(smem + OFF_RM + (m * 16 + l4) * 144 +
                                 s * 64 + g * 16);
  float* cbuf = (float*)wbuf;     // [32][72] f32 = 9216 B, wave-private
  #pragma unroll 1
  for (int grp = 0; grp < 16; ++grp) {
    const int ga = (grp + off2) & 15;           // rotated column group
    const int cbase = wave * 1024 + ga * 64;
    float4 bb[8];
    #pragma unroll
    for (int v2 = 0; v2 < 8; ++v2) {
      const int r = g + v2 * 4;
      bb[v2] = *(const float4*)(base + (rowbase + r) * D_DIM + cbase + l4 * 4);
    }
    f32x4v a[2][4];
    #pragma unroll
    for (int m = 0; m < 2; ++m)
      #pragma unroll
      for (int t = 0; t < 4; ++t) a[m][t] = (f32x4v){0.f, 0.f, 0.f, 0.f};
    #pragma unroll
    for (int t = 0; t < 4; ++t) {
      #pragma unroll
      for (int s = 0; s < 2; ++s) {
        uint4 bfrag;  // B[kk=j][n=col] = W[col][j]
        if (USE_WS) {
          bfrag = *(const uint4*)(Wb_bf + (size_t)(cbase + t * 16 + l4) * R_DIM +
                                  s * 32 + g * 8);
        } else {
          const float* wp = W + (size_t)(cbase + t * 16 + l4) * R_DIM + s * 32 + g * 8;
          float4 wa = *(const float4*)(wp);
          float4 wb2 = *(const float4*)(wp + 4);
          bfrag.x = pack2bf(wa.x, wa.y); bfrag.y = pack2bf(wa.z, wa.w);
          bfrag.z = pack2bf(wb2.x, wb2.y); bfrag.w = pack2bf(wb2.z, wb2.w);
        }
        #pragma unroll
        for (int m = 0; m < 2; ++m)
          a[m][t] = __builtin_amdgcn_mfma_f32_16x16x32_bf16(
              __builtin_bit_cast(bf16vec8, a2[m][s]),
              __builtin_bit_cast(bf16vec8, bfrag), a[m][t], 0, 0, 0);
      }
    }
    #pragma unroll
    for (int m = 0; m < 2; ++m)
      #pragma unroll
      for (int t = 0; t < 4; ++t)
        #pragma unroll
        for (int i = 0; i < 4; ++i)
          cbuf[(m * 16 + g * 4 + i) * 72 + t * 16 + l4] = a[m][t][i];
    #pragma unroll
    for (int v2 = 0; v2 < 8; ++v2) {
      const int r = g + v2 * 4;
      f32x4v cv = *(const f32x4v*)(cbuf + r * 72 + l4 * 4);
      float4 o;
      o.x = cv[0] + bb[v2].x;
      o.y = cv[1] + bb[v2].y;
      o.z = cv[2] + bb[v2].z;
      o.w = cv[3] + bb[v2].w;
      *(float4*)(out + (rowbase + r) * D_DIM + cbase + l4 * 4) = o;
    }
  }
}

extern "C" void kernel_launch(void* const* d_in, const int* in_sizes, int n_in,
                              void* d_out, int out_size, void* d_ws, size_t ws_size,
                              hipStream_t stream) {
  const float* base = (const float*)d_in[0];
  const float* srcp = (const float*)d_in[1];
  const float* W    = (const float*)d_in[2];
  const int*   subs = (const int*)d_in[3];
  float* out = (float*)d_out;

  const int nblocks = 16384 / BM;   // 512
  const size_t wbytes = (size_t)2 * R_DIM * D_DIM * sizeof(unsigned short); // 1 MB
  if (d_ws && ws_size >= wbytes) {
    unsigned short* Wt = (unsigned short*)d_ws;          // [64][4096] bf16
    unsigned short* Wb = Wt + (size_t)R_DIM * D_DIM;     // [4096][64] bf16
    lrri_prep<<<256, 256, 0, stream>>>(W, Wt, Wb);
    lrri_fused<true><<<nblocks, 256, 0, stream>>>(base, srcp, W, subs, Wt, Wb, out);
  } else {
    lrri_fused<false><<<nblocks, 256, 0, stream>>>(base, srcp, W, subs, nullptr, nullptr, out);
  }
}